// Round 1
// baseline (1747.534 us; speedup 1.0000x reference)
//
#include <hip/hip_runtime.h>

#define HH 1024
#define OHW 256
#define TH 16
#define TW 32
#define NR 80    // 4*(TH-1)+20 input-tile rows
#define NC 144   // 4*(TW-1)+20 input-tile cols
#define TS 160   // padded LDS row stride in floats (40 chunks of 4)
#define NTHREADS 128

__constant__ float DEC12c[12] = {
  -1.20162964e-04f,  1.615524292e-03f, -1.0385513306e-02f,  4.3619155884e-02f,
  -1.45397186478e-01f, 6.10668182370e-01f, 6.10668182370e-01f, -1.45397186478e-01f,
   4.3619155884e-02f, -1.0385513306e-02f,  1.615524292e-03f, -1.20162964e-04f
};

// LDS float offset with 4-float-chunk XOR swizzle (bank-cluster spread for b128)
__device__ __forceinline__ int swzoff(int r, int c) {
  return r * TS + ((((c >> 2) ^ ((r >> 2) & 7)) << 2) | (c & 3));
}

__global__ __launch_bounds__(NTHREADS) void dgp_kernel(
    const float* __restrict__ inp, const float* __restrict__ mtfp,
    const int* __restrict__ rp, const int* __restrict__ cp,
    float* __restrict__ outg) {
  __shared__ __align__(16) float tile[NR * TS];
  __shared__ __align__(16) float ck[400];   // combined 20x20 kernel
  __shared__ float kva[180];                // [S=0..19][v=0..8]  sum_p a[p]*mtf[S-p][v]
  __shared__ float khb[180];                // [u=0..8][T=0..19]  sum_q b[q]*mtf[u][T-q]
  __shared__ float mlds[81];                // mtf[u][v] for this channel
  __shared__ float avs[12], bvs[12];

  const int tid = threadIdx.x;
  const int bxt = blockIdx.x, by = blockIdx.y, bz = blockIdx.z;
  const int chC = bz & 7;
  const int rv = rp[bz], cv = cp[bz];
  const int ri = rv >> 1, rf = rv & 1, ci = cv >> 1, cf = cv & 1;
  const int Ri0 = 2 + 4 * TH * by - ri;   // output row oi0 -> x row
  const int Cj0 = 2 + 4 * TW * bxt - ci;
  const int R0 = Ri0 - 10, C0 = Cj0 - 10; // global origin of LDS tile

  // ---- phase 1: tiny tables ----
  if (tid < 12)       avs[tid] = rf ? DEC12c[tid] : (tid == 6 ? 1.f : 0.f);
  else if (tid < 24)  bvs[tid - 12] = cf ? DEC12c[tid - 12] : (tid - 12 == 6 ? 1.f : 0.f);
  else if (tid < 105) { const int m = tid - 24; mlds[m] = mtfp[m * 8 + chC]; }
  __syncthreads();

  // ---- phase 2: 1D-combined tables ----
  for (int i = tid; i < 180; i += NTHREADS) {
    const int S = i / 9, v = i - S * 9;
    const int plo = (S - 8 > 0) ? S - 8 : 0, phi = (S < 11) ? S : 11;
    float s1 = 0.f;
    for (int p = plo; p <= phi; ++p) s1 += avs[p] * mlds[(S - p) * 9 + v];
    kva[i] = s1;
  }
  for (int i = tid; i < 180; i += NTHREADS) {
    const int u = i / 20, T = i - u * 20;
    const int qlo = (T - 8 > 0) ? T - 8 : 0, qhi = (T < 11) ? T : 11;
    float s1 = 0.f;
    for (int q = qlo; q <= qhi; ++q) s1 += bvs[q] * mlds[u * 9 + (T - q)];
    khb[i] = s1;
  }
  __syncthreads();

  // ---- phase 3: 2D combined kernel + stage input tile (clamped) ----
  for (int i = tid; i < 400; i += NTHREADS) {
    const int S = i / 20, T = i - S * 20;
    const int qlo = (T - 8 > 0) ? T - 8 : 0, qhi = (T < 11) ? T : 11;
    float s1 = 0.f;
    for (int q = qlo; q <= qhi; ++q) s1 += bvs[q] * kva[S * 9 + (T - q)];
    ck[i] = s1;
  }
  const float* src = inp + ((size_t)bz << 20);
  for (int i = tid; i < NR * NC; i += NTHREADS) {
    const int rr = i / NC, cc = i - rr * NC;
    int gr = R0 + rr; gr = gr < 0 ? 0 : (gr > 1023 ? 1023 : gr);
    int gc = C0 + cc; gc = gc < 0 ? 0 : (gc > 1023 ? 1023 : gc);
    tile[swzoff(rr, cc)] = src[(gr << 10) + gc];
  }
  __syncthreads();

  // ---- main: each thread computes 4 horizontally adjacent output points ----
  const int ty = tid >> 3;   // 0..15
  const int tx = tid & 7;    // 0..7
  const int rbase = 4 * ty;
  float accA[4] = {0.f, 0.f, 0.f, 0.f}, accB[4] = {0.f, 0.f, 0.f, 0.f};

  #pragma unroll
  for (int s = 0; s < 20; ++s) {
    const int r = rbase + s;
    const int mask = (r >> 2) & 7;
    const float* rowp = tile + r * TS;
    float w[32];
    #pragma unroll
    for (int j = 0; j < 8; ++j) {
      const float4 v = *(const float4*)(rowp + (((4 * tx + j) ^ mask) << 2));
      w[4 * j + 0] = v.x; w[4 * j + 1] = v.y; w[4 * j + 2] = v.z; w[4 * j + 3] = v.w;
    }
    float kr[20];
    #pragma unroll
    for (int j = 0; j < 5; ++j) {
      const float4 v = *(const float4*)(ck + s * 20 + 4 * j);
      kr[4 * j + 0] = v.x; kr[4 * j + 1] = v.y; kr[4 * j + 2] = v.z; kr[4 * j + 3] = v.w;
    }
    #pragma unroll
    for (int t = 0; t < 20; ++t) {
      const float kv = kr[t];
      #pragma unroll
      for (int k = 0; k < 4; ++k) {
        if (t & 1) accB[k] += kv * w[4 * k + t];
        else       accA[k] += kv * w[4 * k + t];
      }
    }
  }

  // ---- epilogue: zero-pad corrections (rare) + store ----
  const int oi = TH * by + ty;
  const int Ri = Ri0 + 4 * ty;
  const bool rowBad = (Ri < 6) || (Ri > 1018);

  #pragma unroll
  for (int k = 0; k < 4; ++k) {
    float res = accA[k] + accB[k];
    const int oj = TW * bxt + 4 * tx + k;
    const int Cj = Cj0 + 4 * (4 * tx + k);
    const bool colBad = (Cj < 6) || (Cj > 1018);
    if (rowBad || colBad) {
      const int cb = 16 * tx + 4 * k;
      float corr = 0.f;
      if (rowBad) {
        #pragma unroll 1
        for (int p = 0; p < 12; ++p) {
          const int xi = Ri + p - 6;
          if (xi >= 0 && xi < HH) continue;  // only invalid (zero-padded) taps
          float s1 = 0.f;
          for (int u = 0; u < 9; ++u)
            for (int T = 0; T < 20; ++T)
              s1 += khb[u * 20 + T] * tile[swzoff(rbase + p + u, cb + T)];
          corr += avs[p] * s1;
        }
      }
      if (colBad) {
        #pragma unroll 1
        for (int q = 0; q < 12; ++q) {
          const int xj = Cj + q - 6;
          if (xj >= 0 && xj < HH) continue;
          float s1 = 0.f;
          for (int S = 0; S < 20; ++S)
            for (int v = 0; v < 9; ++v)
              s1 += kva[S * 9 + v] * tile[swzoff(rbase + S, cb + q + v)];
          corr += bvs[q] * s1;
        }
      }
      if (rowBad && colBad) {  // add back doubly-subtracted taps
        #pragma unroll 1
        for (int p = 0; p < 12; ++p) {
          const int xi = Ri + p - 6;
          if (xi >= 0 && xi < HH) continue;
          #pragma unroll 1
          for (int q = 0; q < 12; ++q) {
            const int xj = Cj + q - 6;
            if (xj >= 0 && xj < HH) continue;
            float s1 = 0.f;
            for (int u = 0; u < 9; ++u)
              for (int v = 0; v < 9; ++v)
                s1 += mlds[u * 9 + v] * tile[swzoff(rbase + p + u, cb + q + v)];
            corr -= avs[p] * bvs[q] * s1;
          }
        }
      }
      res -= corr;
    }
    outg[((size_t)bz * OHW + oi) * OHW + oj] = res;
  }
}

extern "C" void kernel_launch(void* const* d_in, const int* in_sizes, int n_in,
                              void* d_out, int out_size, void* d_ws, size_t ws_size,
                              hipStream_t stream) {
  const float* inp  = (const float*)d_in[0];
  const float* mtfp = (const float*)d_in[1];
  const int*   rp   = (const int*)d_in[2];
  const int*   cp   = (const int*)d_in[3];
  float* outg = (float*)d_out;
  dim3 grid(OHW / TW, OHW / TH, 32);  // (8, 16, B*C)
  dim3 block(NTHREADS);
  hipLaunchKernelGGL(dgp_kernel, grid, block, 0, stream, inp, mtfp, rp, cp, outg);
}

// Round 2
// 1508.765 us; speedup vs baseline: 1.1583x; 1.1583x over previous
//
#include <hip/hip_runtime.h>

#define HH 1024
#define OHW 256
#define TH 16
#define TW 32
#define NR 80    // 4*(TH-1)+20 input-tile rows
#define NCC 36   // chunks of 4 floats per tile row (144 floats)
#define TS 160   // padded LDS row stride in floats (40 chunks)
#define NTHREADS 128

__constant__ float DEC12c[12] = {
  -1.20162964e-04f,  1.615524292e-03f, -1.0385513306e-02f,  4.3619155884e-02f,
  -1.45397186478e-01f, 6.10668182370e-01f, 6.10668182370e-01f, -1.45397186478e-01f,
   4.3619155884e-02f, -1.0385513306e-02f,  1.615524292e-03f, -1.20162964e-04f
};

__device__ __forceinline__ int clampi(int v) { return v < 0 ? 0 : (v > HH - 1 ? HH - 1 : v); }

// ---------------- main kernel: interior formula everywhere ----------------
__global__ __launch_bounds__(NTHREADS) void dgp_main(
    const float* __restrict__ inp, const float* __restrict__ mtfp,
    const int* __restrict__ rp, const int* __restrict__ cp,
    float* __restrict__ outg) {
  __shared__ __align__(16) float tile[NR * TS];
  __shared__ __align__(16) float ck[400];   // combined 20x20 kernel
  __shared__ float kva[180];                // [S][v] = sum_p a[p]*mtf[S-p][v]
  __shared__ float mlds[81];
  __shared__ float avs[12], bvs[12];

  const int tid = threadIdx.x;
  const int bxt = blockIdx.x, by = blockIdx.y, bz = blockIdx.z;
  const int chC = bz & 7;
  const int rv = rp[bz], cv = cp[bz];
  const int ri = rv >> 1, rf = rv & 1, ci = cv >> 1, cf = cv & 1;
  const int Ri0 = 2 + 4 * TH * by - ri;
  const int Cj0 = 2 + 4 * TW * bxt - ci;
  const int R0 = Ri0 - 10, C0 = Cj0 - 10;

  if (tid < 12)       avs[tid] = rf ? DEC12c[tid] : (tid == 6 ? 1.f : 0.f);
  else if (tid < 24)  bvs[tid - 12] = cf ? DEC12c[tid - 12] : (tid - 12 == 6 ? 1.f : 0.f);
  else if (tid < 105) { const int m = tid - 24; mlds[m] = mtfp[m * 8 + chC]; }
  __syncthreads();

  for (int i = tid; i < 180; i += NTHREADS) {
    const int S = i / 9, v = i - S * 9;
    const int plo = (S - 8 > 0) ? S - 8 : 0, phi = (S < 11) ? S : 11;
    float s1 = 0.f;
    for (int p = plo; p <= phi; ++p) s1 += avs[p] * mlds[(S - p) * 9 + v];
    kva[i] = s1;
  }
  __syncthreads();

  for (int i = tid; i < 400; i += NTHREADS) {
    const int S = i / 20, T = i - S * 20;
    const int qlo = (T - 8 > 0) ? T - 8 : 0, qhi = (T < 11) ? T : 11;
    float s1 = 0.f;
    for (int q = qlo; q <= qhi; ++q) s1 += bvs[q] * kva[S * 9 + (T - q)];
    ck[i] = s1;
  }
  // stage 80x144 input tile (edge-clamped), chunked: 4 scalar loads + b128 LDS write
  const float* src = inp + ((size_t)bz << 20);
  for (int idx = tid; idx < NR * NCC; idx += NTHREADS) {
    const int rr = idx / NCC, jc = idx - rr * NCC;
    const int gr = clampi(R0 + rr);
    const float* grow = src + (gr << 10);
    const int c0 = C0 + 4 * jc;
    float4 v;
    v.x = grow[clampi(c0 + 0)];
    v.y = grow[clampi(c0 + 1)];
    v.z = grow[clampi(c0 + 2)];
    v.w = grow[clampi(c0 + 3)];
    *(float4*)(tile + rr * TS + (((jc ^ ((rr >> 2) & 7)) << 2))) = v;
  }
  __syncthreads();

  const int ty = tid >> 3;   // 0..15
  const int tx = tid & 7;    // 0..7
  const int rbase = 4 * ty;
  float acc0[4] = {0.f, 0.f, 0.f, 0.f}, acc1[4] = {0.f, 0.f, 0.f, 0.f};

  #pragma unroll 4
  for (int s = 0; s < 20; ++s) {
    const int r = rbase + s;
    const int mask = (r >> 2) & 7;
    const float* rowp = tile + r * TS;
    float4 kr[5];
    #pragma unroll
    for (int j = 0; j < 5; ++j) kr[j] = *(const float4*)(ck + s * 20 + 4 * j);
    #pragma unroll
    for (int j = 0; j < 8; ++j) {
      const float4 w = *(const float4*)(rowp + (((4 * tx + j) ^ mask) << 2));
      #pragma unroll
      for (int k = 0; k < 4; ++k) {
        const int d = j - k;
        if (d >= 0 && d < 5) {
          const float4 kk = kr[d];
          acc0[k] += kk.x * w.x + kk.z * w.z;
          acc1[k] += kk.y * w.y + kk.w * w.w;
        }
      }
    }
  }

  const int oi = TH * by + ty;
  float* orow = outg + ((size_t)bz * OHW + oi) * OHW + TW * bxt + 4 * tx;
  #pragma unroll
  for (int k = 0; k < 4; ++k) orow[k] = acc0[k] + acc1[k];
}

// ---------------- fixup kernel: recompute boundary outputs exactly ----------------
__global__ __launch_bounds__(256) void dgp_fixup(
    const float* __restrict__ inp, const float* __restrict__ mtfp,
    const int* __restrict__ rp, const int* __restrict__ cp,
    float* __restrict__ outg) {
  __shared__ float mlds[81];
  __shared__ float avs[12], bvs[12];
  const int tid = threadIdx.x;
  const int seg = blockIdx.x;      // 0..5
  const int bz = blockIdx.y;       // 0..31
  const int chC = bz & 7;
  const int rv = rp[bz], cv = cp[bz];
  const int ri = rv >> 1, rf = rv & 1, ci = cv >> 1, cf = cv & 1;

  if (tid < 81)        mlds[tid] = mtfp[tid * 8 + chC];
  else if (tid < 93)   avs[tid - 81] = rf ? DEC12c[tid - 81] : (tid - 81 == 6 ? 1.f : 0.f);
  else if (tid < 105)  bvs[tid - 93] = cf ? DEC12c[tid - 93] : (tid - 93 == 6 ? 1.f : 0.f);
  __syncthreads();

  int oi, oj;
  if (seg < 3) { oi = (seg == 2) ? 255 : seg; oj = tid; }
  else         { oj = (seg == 5) ? 255 : seg - 3; oi = tid; }

  const int Ri = 2 + 4 * oi - ri;
  const int Cj = 2 + 4 * oj - ci;
  const float* src = inp + ((size_t)bz << 20);

  float out = 0.f;
  for (int p = 0; p < 12; ++p) {
    const float ap = avs[p];
    if (ap == 0.f) continue;
    const int xi = Ri - 6 + p;
    if (xi < 0 || xi >= HH) continue;   // interp zero-padding on rows
    float racc = 0.f;
    for (int q = 0; q < 12; ++q) {
      const float bq = bvs[q];
      if (bq == 0.f) continue;
      const int xj = Cj - 6 + q;
      if (xj < 0 || xj >= HH) continue; // interp zero-padding on cols
      float s = 0.f;
      #pragma unroll
      for (int u = 0; u < 9; ++u) {
        const float* grow = src + (clampi(xi - 4 + u) << 10);
        #pragma unroll
        for (int v = 0; v < 9; ++v)
          s += mlds[u * 9 + v] * grow[clampi(xj - 4 + v)];
      }
      racc += bq * s;
    }
    out += ap * racc;
  }
  outg[((size_t)bz * OHW + oi) * OHW + oj] = out;
}

extern "C" void kernel_launch(void* const* d_in, const int* in_sizes, int n_in,
                              void* d_out, int out_size, void* d_ws, size_t ws_size,
                              hipStream_t stream) {
  const float* inp  = (const float*)d_in[0];
  const float* mtfp = (const float*)d_in[1];
  const int*   rp   = (const int*)d_in[2];
  const int*   cp   = (const int*)d_in[3];
  float* outg = (float*)d_out;
  hipLaunchKernelGGL(dgp_main, dim3(OHW / TW, OHW / TH, 32), dim3(NTHREADS), 0, stream,
                     inp, mtfp, rp, cp, outg);
  hipLaunchKernelGGL(dgp_fixup, dim3(6, 32), dim3(256), 0, stream,
                     inp, mtfp, rp, cp, outg);
}

// Round 5
// 231.282 us; speedup vs baseline: 7.5559x; 6.5235x over previous
//
#include <hip/hip_runtime.h>

#define HH 1024
#define OHW 256
#define TH 16
#define TW 32
#define NR 80    // 4*(TH-1)+20 input-tile rows
#define NCC 36   // chunks of 4 floats per tile row (144 floats)
#define TS 160   // padded LDS row stride in floats (40 chunks)
#define NTHREADS 128
#define ESPAN 528          // edgefix staged strip length (floats)
#define ECHUNK (ESPAN/4)   // 132

__constant__ float DEC12c[12] = {
  -1.20162964e-04f,  1.615524292e-03f, -1.0385513306e-02f,  4.3619155884e-02f,
  -1.45397186478e-01f, 6.10668182370e-01f, 6.10668182370e-01f, -1.45397186478e-01f,
   4.3619155884e-02f, -1.0385513306e-02f,  1.615524292e-03f, -1.20162964e-04f
};

__device__ __forceinline__ int clampi(int v) { return v < 0 ? 0 : (v > HH - 1 ? HH - 1 : v); }

// ---------------- main kernel: interior formula everywhere ----------------
__global__ __launch_bounds__(NTHREADS) void dgp_main(
    const float* __restrict__ inp, const float* __restrict__ mtfp,
    const int* __restrict__ rp, const int* __restrict__ cp,
    float* __restrict__ outg) {
  __shared__ __align__(16) float tile[NR * TS];
  __shared__ __align__(16) float ck[400];   // combined 20x20 kernel
  __shared__ float kva[180];                // [S][v] = sum_p a[p]*mtf[S-p][v]
  __shared__ float mlds[81];
  __shared__ float avs[12], bvs[12];

  const int tid = threadIdx.x;
  const int bxt = blockIdx.x, by = blockIdx.y, bz = blockIdx.z;
  const int chC = bz & 7;
  const int rv = rp[bz], cv = cp[bz];
  const int ri = rv >> 1, rf = rv & 1, ci = cv >> 1, cf = cv & 1;
  const int Ri0 = 2 + 4 * TH * by - ri;
  const int Cj0 = 2 + 4 * TW * bxt - ci;
  const int R0 = Ri0 - 10, C0 = Cj0 - 10;

  if (tid < 12)       avs[tid] = rf ? DEC12c[tid] : (tid == 6 ? 1.f : 0.f);
  else if (tid < 24)  bvs[tid - 12] = cf ? DEC12c[tid - 12] : (tid - 12 == 6 ? 1.f : 0.f);
  else if (tid < 105) { const int m = tid - 24; mlds[m] = mtfp[m * 8 + chC]; }
  __syncthreads();

  for (int i = tid; i < 180; i += NTHREADS) {
    const int S = i / 9, v = i - S * 9;
    const int plo = (S - 8 > 0) ? S - 8 : 0, phi = (S < 11) ? S : 11;
    float s1 = 0.f;
    for (int p = plo; p <= phi; ++p) s1 += avs[p] * mlds[(S - p) * 9 + v];
    kva[i] = s1;
  }
  __syncthreads();

  for (int i = tid; i < 400; i += NTHREADS) {
    const int S = i / 20, T = i - S * 20;
    const int qlo = (T - 8 > 0) ? T - 8 : 0, qhi = (T < 11) ? T : 11;
    float s1 = 0.f;
    for (int q = qlo; q <= qhi; ++q) s1 += bvs[q] * kva[S * 9 + (T - q)];
    ck[i] = s1;
  }
  // stage 80x144 input tile (edge-clamped), chunked: 4 scalar loads + b128 LDS write
  const float* src = inp + ((size_t)bz << 20);
  for (int idx = tid; idx < NR * NCC; idx += NTHREADS) {
    const int rr = idx / NCC, jc = idx - rr * NCC;
    const int gr = clampi(R0 + rr);
    const float* grow = src + (gr << 10);
    const int c0 = C0 + 4 * jc;
    float4 v;
    v.x = grow[clampi(c0 + 0)];
    v.y = grow[clampi(c0 + 1)];
    v.z = grow[clampi(c0 + 2)];
    v.w = grow[clampi(c0 + 3)];
    *(float4*)(tile + rr * TS + (((jc ^ ((rr >> 2) & 7)) << 2))) = v;
  }
  __syncthreads();

  const int ty = tid >> 3;   // 0..15
  const int tx = tid & 7;    // 0..7
  const int rbase = 4 * ty;
  float acc0[4] = {0.f, 0.f, 0.f, 0.f}, acc1[4] = {0.f, 0.f, 0.f, 0.f};

  #pragma unroll 4
  for (int s = 0; s < 20; ++s) {
    const int r = rbase + s;
    const int mask = (r >> 2) & 7;
    const float* rowp = tile + r * TS;
    float4 kr[5];
    #pragma unroll
    for (int j = 0; j < 5; ++j) kr[j] = *(const float4*)(ck + s * 20 + 4 * j);
    #pragma unroll
    for (int j = 0; j < 8; ++j) {
      const float4 w = *(const float4*)(rowp + (((4 * tx + j) ^ mask) << 2));
      #pragma unroll
      for (int k = 0; k < 4; ++k) {
        const int d = j - k;
        if (d >= 0 && d < 5) {
          const float4 kk = kr[d];
          acc0[k] += kk.x * w.x + kk.z * w.z;
          acc1[k] += kk.y * w.y + kk.w * w.w;
        }
      }
    }
  }

  const int oi = TH * by + ty;
  float* orow = outg + ((size_t)bz * OHW + oi) * OHW + TW * bxt + 4 * tx;
  #pragma unroll
  for (int k = 0; k < 4; ++k) orow[k] = acc0[k] + acc1[k];
}

// ---------------- edge fixup: masked-separable recompute of rows/cols {0,1,255} ----------------
// grid (2, 6, 32): x = half (128 points), y<3 row-segment else col-segment, z = b*c image
__global__ __launch_bounds__(NTHREADS) void dgp_edgefix(
    const float* __restrict__ inp, const float* __restrict__ mtfp,
    const int* __restrict__ rp, const int* __restrict__ cp,
    float* __restrict__ outg) {
  __shared__ __align__(16) float tile[20 * ESPAN];
  __shared__ __align__(16) float ck[400];
  __shared__ float kva[180];
  __shared__ float mlds[81];
  __shared__ float avs[12], bvs[12];

  const int tid = threadIdx.x;
  const int bx = blockIdx.x, by = blockIdx.y, bz = blockIdx.z;
  const bool isRow = (by < 3);
  const int segi = isRow ? by : by - 3;
  const int fixedo = (segi == 2) ? 255 : segi;   // the fixed oi (row) or oj (col)
  const int chC = bz & 7;
  const int rv = rp[bz], cv = cp[bz];
  const int ri = rv >> 1, rf = rv & 1, ci = cv >> 1, cf = cv & 1;

  // masked tap vectors: zero taps whose interp source index is zero-padded
  if (tid < 12) {
    float av = rf ? DEC12c[tid] : (tid == 6 ? 1.f : 0.f);
    if (isRow) {
      const int xi = (2 + 4 * fixedo - ri) - 6 + tid;
      if (xi < 0 || xi >= HH) av = 0.f;
    }
    avs[tid] = av;
  } else if (tid < 24) {
    const int q = tid - 12;
    float bv = cf ? DEC12c[q] : (q == 6 ? 1.f : 0.f);
    if (!isRow) {
      const int xj = (2 + 4 * fixedo - ci) - 6 + q;
      if (xj < 0 || xj >= HH) bv = 0.f;
    }
    bvs[q] = bv;
  } else if (tid < 105) {
    const int m = tid - 24; mlds[m] = mtfp[m * 8 + chC];
  }
  __syncthreads();

  for (int i = tid; i < 180; i += NTHREADS) {
    const int S = i / 9, v = i - S * 9;
    const int plo = (S - 8 > 0) ? S - 8 : 0, phi = (S < 11) ? S : 11;
    float s1 = 0.f;
    for (int p = plo; p <= phi; ++p) s1 += avs[p] * mlds[(S - p) * 9 + v];
    kva[i] = s1;
  }
  __syncthreads();
  for (int i = tid; i < 400; i += NTHREADS) {
    const int S = i / 20, T = i - S * 20;
    const int qlo = (T - 8 > 0) ? T - 8 : 0, qhi = (T < 11) ? T : 11;
    float s1 = 0.f;
    for (int q = qlo; q <= qhi; ++q) s1 += bvs[q] * kva[S * 9 + (T - q)];
    ck[i] = s1;
  }

  const float* src = inp + ((size_t)bz << 20);
  if (isRow) {
    // stage 20 rows x 528 cols, row-major coalesced
    const int R0 = (2 + 4 * fixedo - ri) - 10;
    const int C0c = 512 * bx - 8 - ci;
    for (int i = tid; i < 20 * ECHUNK; i += NTHREADS) {
      const int rr = i / ECHUNK, jc = i - rr * ECHUNK;
      const float* grow = src + (clampi(R0 + rr) << 10);
      const int c0 = C0c + 4 * jc;
      float4 v;
      v.x = grow[clampi(c0 + 0)];
      v.y = grow[clampi(c0 + 1)];
      v.z = grow[clampi(c0 + 2)];
      v.w = grow[clampi(c0 + 3)];
      *(float4*)(tile + rr * ESPAN + 4 * jc) = v;
    }
  } else {
    // stage transposed: 20 cols x 528 rows
    const int Cw0 = (2 + 4 * fixedo - ci) - 10;
    const int Rr0 = 512 * bx - 8 - ri;
    for (int i = tid; i < 20 * ESPAN; i += NTHREADS) {
      const int T = i / ESPAN, rr = i - T * ESPAN;
      tile[T * ESPAN + rr] = src[(clampi(Rr0 + rr) << 10) + clampi(Cw0 + T)];
    }
  }
  __syncthreads();

  // compute: 20 strips x 20-float window per thread (16B-aligned at 4*tid)
  float acc = 0.f;
  #pragma unroll 4
  for (int L = 0; L < 20; ++L) {
    const float* wp = tile + L * ESPAN + 4 * tid;
    float w[20];
    #pragma unroll
    for (int j = 0; j < 5; ++j) {
      const float4 v = *(const float4*)(wp + 4 * j);
      w[4 * j] = v.x; w[4 * j + 1] = v.y; w[4 * j + 2] = v.z; w[4 * j + 3] = v.w;
    }
    if (isRow) {
      #pragma unroll
      for (int e = 0; e < 20; ++e) acc += ck[L * 20 + e] * w[e];   // L=S, e=T
    } else {
      #pragma unroll
      for (int e = 0; e < 20; ++e) acc += ck[e * 20 + L] * w[e];   // L=T, e=S
    }
  }

  int oi, oj;
  if (isRow) { oi = fixedo; oj = 128 * bx + tid; }
  else       { oj = fixedo; oi = 128 * bx + tid; }
  outg[((size_t)bz * OHW + oi) * OHW + oj] = acc;
}

// ---------------- corner fixup: 9 points/image, exact double-masked sum ----------------
// grid (3, 3, 32), block 64: one wave per corner point, lanes split the 144 (p,q) taps
__global__ __launch_bounds__(64) void dgp_cornerfix(
    const float* __restrict__ inp, const float* __restrict__ mtfp,
    const int* __restrict__ rp, const int* __restrict__ cp,
    float* __restrict__ outg) {
  __shared__ float mlds[81];
  __shared__ float avs[12], bvs[12];
  const int lane = threadIdx.x;
  const int bi = blockIdx.x, bj = blockIdx.y, bz = blockIdx.z;
  const int oi = (bi == 2) ? 255 : bi;
  const int oj = (bj == 2) ? 255 : bj;
  const int chC = bz & 7;
  const int rv = rp[bz], cv = cp[bz];
  const int ri = rv >> 1, rf = rv & 1, ci = cv >> 1, cf = cv & 1;

  if (lane < 12)       avs[lane] = rf ? DEC12c[lane] : (lane == 6 ? 1.f : 0.f);
  else if (lane < 24)  bvs[lane - 12] = cf ? DEC12c[lane - 12] : (lane - 12 == 6 ? 1.f : 0.f);
  for (int m = lane; m < 81; m += 64) mlds[m] = mtfp[m * 8 + chC];
  __syncthreads();

  const int Ri = 2 + 4 * oi - ri;
  const int Cj = 2 + 4 * oj - ci;
  const float* src = inp + ((size_t)bz << 20);

  float acc = 0.f;
  for (int pair = lane; pair < 144; pair += 64) {
    const int p = pair / 12, q = pair - 12 * (pair / 12);
    const int xi = Ri - 6 + p, xj = Cj - 6 + q;
    if (xi < 0 || xi >= HH || xj < 0 || xj >= HH) continue;
    const float ab = avs[p] * bvs[q];
    if (ab == 0.f) continue;
    float s = 0.f;
    #pragma unroll
    for (int u = 0; u < 9; ++u) {
      const float* grow = src + (clampi(xi - 4 + u) << 10);
      #pragma unroll
      for (int v = 0; v < 9; ++v) s += mlds[u * 9 + v] * grow[clampi(xj - 4 + v)];
    }
    acc += ab * s;
  }
  #pragma unroll
  for (int off = 32; off > 0; off >>= 1) acc += __shfl_down(acc, off);
  if (lane == 0) outg[((size_t)bz * OHW + oi) * OHW + oj] = acc;
}

extern "C" void kernel_launch(void* const* d_in, const int* in_sizes, int n_in,
                              void* d_out, int out_size, void* d_ws, size_t ws_size,
                              hipStream_t stream) {
  const float* inp  = (const float*)d_in[0];
  const float* mtfp = (const float*)d_in[1];
  const int*   rp   = (const int*)d_in[2];
  const int*   cp   = (const int*)d_in[3];
  float* outg = (float*)d_out;
  hipLaunchKernelGGL(dgp_main, dim3(OHW / TW, OHW / TH, 32), dim3(NTHREADS), 0, stream,
                     inp, mtfp, rp, cp, outg);
  hipLaunchKernelGGL(dgp_edgefix, dim3(2, 6, 32), dim3(NTHREADS), 0, stream,
                     inp, mtfp, rp, cp, outg);
  hipLaunchKernelGGL(dgp_cornerfix, dim3(3, 3, 32), dim3(64), 0, stream,
                     inp, mtfp, rp, cp, outg);
}

// Round 6
// 157.904 us; speedup vs baseline: 11.0671x; 1.4647x over previous
//
#include <hip/hip_runtime.h>

typedef _Float16 half2v __attribute__((ext_vector_type(2)));

#define HH 1024
#define OHW 256
#define TH 16
#define TW 32
#define NR 80        // input-tile rows
#define NCH 18       // data chunks (8 halves) per row = 144 cols
#define TCH 24       // padded chunks per row (XOR swizzle headroom)
#define ROWH (TCH*8) // 192 halves per row
#define NTHREADS 128
#define ESPAN 528
#define ECHUNK (ESPAN/4)

#if defined(__has_builtin)
#  if __has_builtin(__builtin_amdgcn_fdot2)
#    define HAS_FDOT2 1
#  endif
#endif
#ifndef HAS_FDOT2
#  define HAS_FDOT2 0
#endif

__constant__ float DEC12c[12] = {
  -1.20162964e-04f,  1.615524292e-03f, -1.0385513306e-02f,  4.3619155884e-02f,
  -1.45397186478e-01f, 6.10668182370e-01f, 6.10668182370e-01f, -1.45397186478e-01f,
   4.3619155884e-02f, -1.0385513306e-02f,  1.615524292e-03f, -1.20162964e-04f
};

__device__ __forceinline__ int clampi(int v) { return v < 0 ? 0 : (v > HH - 1 ? HH - 1 : v); }

// ---------------- main kernel: interior formula, f16 tile + dot2 ----------------
__global__ __launch_bounds__(NTHREADS, 2) void dgp_main(
    const float* __restrict__ inp, const float* __restrict__ mtfp,
    const int* __restrict__ rp, const int* __restrict__ cp,
    float* __restrict__ outg) {
  __shared__ __align__(16) _Float16 tile[NR * ROWH];   // 30720 B
  __shared__ __align__(16) half2v ckh[20 * 16];        // row stride 16 half2 (10 used)
  __shared__ float kva[180];                           // [S][v] f32
  __shared__ float mlds[81];
  __shared__ float avs[12], bvs[12];

  const int tid = threadIdx.x;
  const int bxt = blockIdx.x, by = blockIdx.y, bz = blockIdx.z;
  const int chC = bz & 7;
  const int rv = rp[bz], cv = cp[bz];
  const int ri = rv >> 1, rf = rv & 1, ci = cv >> 1, cf = cv & 1;
  const int Ri0 = 2 + 4 * TH * by - ri;
  const int Cj0 = 2 + 4 * TW * bxt - ci;
  const int R0 = Ri0 - 10, C0 = Cj0 - 10;

  if (tid < 12)       avs[tid] = rf ? DEC12c[tid] : (tid == 6 ? 1.f : 0.f);
  else if (tid < 24)  bvs[tid - 12] = cf ? DEC12c[tid - 12] : (tid - 12 == 6 ? 1.f : 0.f);
  else if (tid < 105) { const int m = tid - 24; mlds[m] = mtfp[m * 8 + chC]; }
  __syncthreads();

  for (int i = tid; i < 180; i += NTHREADS) {
    const int S = i / 9, v = i - S * 9;
    const int plo = (S - 8 > 0) ? S - 8 : 0, phi = (S < 11) ? S : 11;
    float s1 = 0.f;
    for (int p = plo; p <= phi; ++p) s1 += avs[p] * mlds[(S - p) * 9 + v];
    kva[i] = s1;
  }
  __syncthreads();

  // combined 20x20 kernel, packed directly to half2 pairs
  for (int i = tid; i < 200; i += NTHREADS) {
    const int S = i / 10, m = i - S * 10;
    float s[2];
    #pragma unroll
    for (int h = 0; h < 2; ++h) {
      const int T = 2 * m + h;
      const int qlo = (T - 8 > 0) ? T - 8 : 0, qhi = (T < 11) ? T : 11;
      float acc = 0.f;
      for (int q = qlo; q <= qhi; ++q) acc += bvs[q] * kva[S * 9 + (T - q)];
      s[h] = acc;
    }
    half2v hv; hv.x = (_Float16)s[0]; hv.y = (_Float16)s[1];
    ckh[S * 16 + m] = hv;
  }

  // stage 80x144 tile as f16, XOR-swizzled chunks; fast path when cols interior
  const float* src = inp + ((size_t)bz << 20);
  const bool colInt = (C0 >= 0) && (C0 + NCH * 8 - 1 <= HH - 1);
  for (int idx = tid; idx < NR * NCH; idx += NTHREADS) {
    const int rr = idx / NCH, g = idx - rr * NCH;
    const float* grow = src + (clampi(R0 + rr) << 10);
    const int c0 = C0 + 8 * g;
    float v[8];
    if (colInt) {
      __builtin_memcpy(v, grow + c0, 32);
    } else {
      #pragma unroll
      for (int i = 0; i < 8; ++i) v[i] = grow[clampi(c0 + i)];
    }
    _Float16 h[8];
    #pragma unroll
    for (int i = 0; i < 8; ++i) h[i] = (_Float16)v[i];
    __builtin_memcpy(tile + rr * ROWH + ((g ^ ((rr >> 2) & 7)) << 3), h, 16);
  }
  __syncthreads();

  const int ty = tid >> 3;   // 0..15
  const int tx = tid & 7;    // 0..7
  const int rbase = 4 * ty;
  float accA[4] = {0.f, 0.f, 0.f, 0.f}, accB[4] = {0.f, 0.f, 0.f, 0.f};

  #pragma unroll 4
  for (int s = 0; s < 20; ++s) {
    const int r = rbase + s;
    const int mask = (r >> 2) & 7;
    const _Float16* rowp = tile + r * ROWH;
    half2v kr2[10];
    __builtin_memcpy(kr2, &ckh[s * 16], 40);
    half2v w2[16];
    #pragma unroll
    for (int j = 0; j < 4; ++j) {
      const int c = (2 * tx + j) ^ mask;
      __builtin_memcpy(&w2[4 * j], rowp + (c << 3), 16);
    }
    #pragma unroll
    for (int k = 0; k < 4; ++k) {
      #pragma unroll
      for (int m = 0; m < 10; ++m) {
#if HAS_FDOT2
        if (m & 1) accB[k] = __builtin_amdgcn_fdot2(w2[2 * k + m], kr2[m], accB[k], false);
        else       accA[k] = __builtin_amdgcn_fdot2(w2[2 * k + m], kr2[m], accA[k], false);
#else
        const float t = (float)w2[2 * k + m].x * (float)kr2[m].x
                      + (float)w2[2 * k + m].y * (float)kr2[m].y;
        if (m & 1) accB[k] += t; else accA[k] += t;
#endif
      }
    }
  }

  const int oi = TH * by + ty;
  float* orow = outg + ((size_t)bz * OHW + oi) * OHW + TW * bxt + 4 * tx;
  #pragma unroll
  for (int k = 0; k < 4; ++k) orow[k] = accA[k] + accB[k];
}

// ---------------- edge fixup: masked-separable recompute of rows/cols {0,1,255} ----------------
__global__ __launch_bounds__(NTHREADS) void dgp_edgefix(
    const float* __restrict__ inp, const float* __restrict__ mtfp,
    const int* __restrict__ rp, const int* __restrict__ cp,
    float* __restrict__ outg) {
  __shared__ __align__(16) float tile[20 * ESPAN];
  __shared__ __align__(16) float ck[400];
  __shared__ float kva[180];
  __shared__ float mlds[81];
  __shared__ float avs[12], bvs[12];

  const int tid = threadIdx.x;
  const int bx = blockIdx.x, by = blockIdx.y, bz = blockIdx.z;
  const bool isRow = (by < 3);
  const int segi = isRow ? by : by - 3;
  const int fixedo = (segi == 2) ? 255 : segi;
  const int chC = bz & 7;
  const int rv = rp[bz], cv = cp[bz];
  const int ri = rv >> 1, rf = rv & 1, ci = cv >> 1, cf = cv & 1;

  if (tid < 12) {
    float av = rf ? DEC12c[tid] : (tid == 6 ? 1.f : 0.f);
    if (isRow) {
      const int xi = (2 + 4 * fixedo - ri) - 6 + tid;
      if (xi < 0 || xi >= HH) av = 0.f;
    }
    avs[tid] = av;
  } else if (tid < 24) {
    const int q = tid - 12;
    float bv = cf ? DEC12c[q] : (q == 6 ? 1.f : 0.f);
    if (!isRow) {
      const int xj = (2 + 4 * fixedo - ci) - 6 + q;
      if (xj < 0 || xj >= HH) bv = 0.f;
    }
    bvs[q] = bv;
  } else if (tid < 105) {
    const int m = tid - 24; mlds[m] = mtfp[m * 8 + chC];
  }
  __syncthreads();

  for (int i = tid; i < 180; i += NTHREADS) {
    const int S = i / 9, v = i - S * 9;
    const int plo = (S - 8 > 0) ? S - 8 : 0, phi = (S < 11) ? S : 11;
    float s1 = 0.f;
    for (int p = plo; p <= phi; ++p) s1 += avs[p] * mlds[(S - p) * 9 + v];
    kva[i] = s1;
  }
  __syncthreads();
  for (int i = tid; i < 400; i += NTHREADS) {
    const int S = i / 20, T = i - S * 20;
    const int qlo = (T - 8 > 0) ? T - 8 : 0, qhi = (T < 11) ? T : 11;
    float s1 = 0.f;
    for (int q = qlo; q <= qhi; ++q) s1 += bvs[q] * kva[S * 9 + (T - q)];
    ck[i] = s1;
  }

  const float* src = inp + ((size_t)bz << 20);
  if (isRow) {
    const int R0 = (2 + 4 * fixedo - ri) - 10;
    const int C0c = 512 * bx - 8 - ci;
    for (int i = tid; i < 20 * ECHUNK; i += NTHREADS) {
      const int rr = i / ECHUNK, jc = i - rr * ECHUNK;
      const float* grow = src + (clampi(R0 + rr) << 10);
      const int c0 = C0c + 4 * jc;
      float4 v;
      v.x = grow[clampi(c0 + 0)];
      v.y = grow[clampi(c0 + 1)];
      v.z = grow[clampi(c0 + 2)];
      v.w = grow[clampi(c0 + 3)];
      *(float4*)(tile + rr * ESPAN + 4 * jc) = v;
    }
  } else {
    const int Cw0 = (2 + 4 * fixedo - ci) - 10;
    const int Rr0 = 512 * bx - 8 - ri;
    for (int i = tid; i < 20 * ESPAN; i += NTHREADS) {
      const int T = i / ESPAN, rr = i - T * ESPAN;
      tile[T * ESPAN + rr] = src[(clampi(Rr0 + rr) << 10) + clampi(Cw0 + T)];
    }
  }
  __syncthreads();

  float acc = 0.f;
  #pragma unroll 4
  for (int L = 0; L < 20; ++L) {
    const float* wp = tile + L * ESPAN + 4 * tid;
    float w[20];
    #pragma unroll
    for (int j = 0; j < 5; ++j) {
      const float4 v = *(const float4*)(wp + 4 * j);
      w[4 * j] = v.x; w[4 * j + 1] = v.y; w[4 * j + 2] = v.z; w[4 * j + 3] = v.w;
    }
    if (isRow) {
      #pragma unroll
      for (int e = 0; e < 20; ++e) acc += ck[L * 20 + e] * w[e];
    } else {
      #pragma unroll
      for (int e = 0; e < 20; ++e) acc += ck[e * 20 + L] * w[e];
    }
  }

  int oi, oj;
  if (isRow) { oi = fixedo; oj = 128 * bx + tid; }
  else       { oj = fixedo; oi = 128 * bx + tid; }
  outg[((size_t)bz * OHW + oi) * OHW + oj] = acc;
}

// ---------------- corner fixup ----------------
__global__ __launch_bounds__(64) void dgp_cornerfix(
    const float* __restrict__ inp, const float* __restrict__ mtfp,
    const int* __restrict__ rp, const int* __restrict__ cp,
    float* __restrict__ outg) {
  __shared__ float mlds[81];
  __shared__ float avs[12], bvs[12];
  const int lane = threadIdx.x;
  const int bi = blockIdx.x, bj = blockIdx.y, bz = blockIdx.z;
  const int oi = (bi == 2) ? 255 : bi;
  const int oj = (bj == 2) ? 255 : bj;
  const int chC = bz & 7;
  const int rv = rp[bz], cv = cp[bz];
  const int ri = rv >> 1, rf = rv & 1, ci = cv >> 1, cf = cv & 1;

  if (lane < 12)       avs[lane] = rf ? DEC12c[lane] : (lane == 6 ? 1.f : 0.f);
  else if (lane < 24)  bvs[lane - 12] = cf ? DEC12c[lane - 12] : (lane - 12 == 6 ? 1.f : 0.f);
  for (int m = lane; m < 81; m += 64) mlds[m] = mtfp[m * 8 + chC];
  __syncthreads();

  const int Ri = 2 + 4 * oi - ri;
  const int Cj = 2 + 4 * oj - ci;
  const float* src = inp + ((size_t)bz << 20);

  float acc = 0.f;
  for (int pair = lane; pair < 144; pair += 64) {
    const int p = pair / 12, q = pair - 12 * (pair / 12);
    const int xi = Ri - 6 + p, xj = Cj - 6 + q;
    if (xi < 0 || xi >= HH || xj < 0 || xj >= HH) continue;
    const float ab = avs[p] * bvs[q];
    if (ab == 0.f) continue;
    float s = 0.f;
    #pragma unroll
    for (int u = 0; u < 9; ++u) {
      const float* grow = src + (clampi(xi - 4 + u) << 10);
      #pragma unroll
      for (int v = 0; v < 9; ++v) s += mlds[u * 9 + v] * grow[clampi(xj - 4 + v)];
    }
    acc += ab * s;
  }
  #pragma unroll
  for (int off = 32; off > 0; off >>= 1) acc += __shfl_down(acc, off);
  if (lane == 0) outg[((size_t)bz * OHW + oi) * OHW + oj] = acc;
}

extern "C" void kernel_launch(void* const* d_in, const int* in_sizes, int n_in,
                              void* d_out, int out_size, void* d_ws, size_t ws_size,
                              hipStream_t stream) {
  const float* inp  = (const float*)d_in[0];
  const float* mtfp = (const float*)d_in[1];
  const int*   rp   = (const int*)d_in[2];
  const int*   cp   = (const int*)d_in[3];
  float* outg = (float*)d_out;
  hipLaunchKernelGGL(dgp_main, dim3(OHW / TW, OHW / TH, 32), dim3(NTHREADS), 0, stream,
                     inp, mtfp, rp, cp, outg);
  hipLaunchKernelGGL(dgp_edgefix, dim3(2, 6, 32), dim3(NTHREADS), 0, stream,
                     inp, mtfp, rp, cp, outg);
  hipLaunchKernelGGL(dgp_cornerfix, dim3(3, 3, 32), dim3(64), 0, stream,
                     inp, mtfp, rp, cp, outg);
}

// Round 7
// 155.710 us; speedup vs baseline: 11.2230x; 1.0141x over previous
//
#include <hip/hip_runtime.h>

typedef _Float16 half2v __attribute__((ext_vector_type(2)));

#define HH 1024
#define OHW 256
#define TH 16
#define TW 64
#define NR 80        // input-tile rows
#define NCH 34       // data chunks (8 halves) per row = 272 cols
#define TCHP 36      // padded chunks per row
#define ROWH (TCHP*8) // 288 halves per row (576 B = 144 dw == 16 mod 32 banks)
#define NTHREADS 256
#define ESPAN 528
#define ECHUNK (ESPAN/4)

#if defined(__has_builtin)
#  if __has_builtin(__builtin_amdgcn_fdot2)
#    define HAS_FDOT2 1
#  endif
#endif
#ifndef HAS_FDOT2
#  define HAS_FDOT2 0
#endif

__constant__ float DEC12c[12] = {
  -1.20162964e-04f,  1.615524292e-03f, -1.0385513306e-02f,  4.3619155884e-02f,
  -1.45397186478e-01f, 6.10668182370e-01f, 6.10668182370e-01f, -1.45397186478e-01f,
   4.3619155884e-02f, -1.0385513306e-02f,  1.615524292e-03f, -1.20162964e-04f
};

__device__ __forceinline__ int clampi(int v) { return v < 0 ? 0 : (v > HH - 1 ? HH - 1 : v); }

// chunk swizzle: spread same-row lanes over all 8 bank-spans, vary per 4-row group
__device__ __forceinline__ int swzc(int c, int r) {
  return c ^ ((c >> 3) & 1) ^ ((r >> 2) & 3);
}

// ---------------- main kernel: interior formula, f16 tile + dot2, 256 thr ----------------
__global__ __launch_bounds__(NTHREADS, 3) void dgp_main(
    const float* __restrict__ inp, const float* __restrict__ mtfp,
    const int* __restrict__ rp, const int* __restrict__ cp,
    float* __restrict__ outg) {
  __shared__ __align__(16) _Float16 tile[NR * ROWH];   // 46080 B
  __shared__ __align__(16) half2v ckh[20 * 16];        // row stride 16 half2 (10 used)
  __shared__ float kva[180];
  __shared__ float mlds[81];
  __shared__ float avs[12], bvs[12];

  const int tid = threadIdx.x;
  const int bxt = blockIdx.x, by = blockIdx.y, bz = blockIdx.z;
  const int chC = bz & 7;
  const int rv = rp[bz], cv = cp[bz];
  const int ri = rv >> 1, rf = rv & 1, ci = cv >> 1, cf = cv & 1;
  const int Ri0 = 2 + 4 * TH * by - ri;
  const int Cj0 = 2 + 4 * TW * bxt - ci;
  const int R0 = Ri0 - 10, C0 = Cj0 - 10;

  if (tid < 12)       avs[tid] = rf ? DEC12c[tid] : (tid == 6 ? 1.f : 0.f);
  else if (tid < 24)  bvs[tid - 12] = cf ? DEC12c[tid - 12] : (tid - 12 == 6 ? 1.f : 0.f);
  else if (tid < 105) { const int m = tid - 24; mlds[m] = mtfp[m * 8 + chC]; }
  __syncthreads();

  for (int i = tid; i < 180; i += NTHREADS) {
    const int S = i / 9, v = i - S * 9;
    const int plo = (S - 8 > 0) ? S - 8 : 0, phi = (S < 11) ? S : 11;
    float s1 = 0.f;
    for (int p = plo; p <= phi; ++p) s1 += avs[p] * mlds[(S - p) * 9 + v];
    kva[i] = s1;
  }
  __syncthreads();

  // combined 20x20 kernel, packed to half2 pairs
  for (int i = tid; i < 200; i += NTHREADS) {
    const int S = i / 10, m = i - S * 10;
    float s[2];
    #pragma unroll
    for (int h = 0; h < 2; ++h) {
      const int T = 2 * m + h;
      const int qlo = (T - 8 > 0) ? T - 8 : 0, qhi = (T < 11) ? T : 11;
      float acc = 0.f;
      for (int q = qlo; q <= qhi; ++q) acc += bvs[q] * kva[S * 9 + (T - q)];
      s[h] = acc;
    }
    half2v hv; hv.x = (_Float16)s[0]; hv.y = (_Float16)s[1];
    ckh[S * 16 + m] = hv;
  }

  // stage 80x272 tile as f16, swizzled chunks; per-chunk interior fast path
  const float* src = inp + ((size_t)bz << 20);
  for (int idx = tid; idx < NR * NCH; idx += NTHREADS) {
    const int rr = idx / NCH, g = idx - rr * NCH;
    const float* grow = src + (clampi(R0 + rr) << 10);
    const int c0 = C0 + 8 * g;
    float v[8];
    if (c0 >= 0 && c0 + 7 <= HH - 1) {
      __builtin_memcpy(v, grow + c0, 32);
    } else {
      #pragma unroll
      for (int i = 0; i < 8; ++i) v[i] = grow[clampi(c0 + i)];
    }
    _Float16 h[8];
    #pragma unroll
    for (int i = 0; i < 8; ++i) h[i] = (_Float16)v[i];
    __builtin_memcpy(tile + rr * ROWH + (swzc(g, rr) << 3), h, 16);
  }
  __syncthreads();

  const int ty = tid >> 4;   // 0..15
  const int tx = tid & 15;   // 0..15
  const int rbase = 4 * ty;
  float accA[4] = {0.f, 0.f, 0.f, 0.f}, accB[4] = {0.f, 0.f, 0.f, 0.f};

  #pragma unroll 4
  for (int s = 0; s < 20; ++s) {
    const int r = rbase + s;
    const _Float16* rowp = tile + r * ROWH;
    half2v kr2[10];
    __builtin_memcpy(kr2, &ckh[s * 16], 40);
    half2v w2[16];
    #pragma unroll
    for (int j = 0; j < 4; ++j) {
      const int c = swzc(2 * tx + j, r);
      __builtin_memcpy(&w2[4 * j], rowp + (c << 3), 16);
    }
    #pragma unroll
    for (int k = 0; k < 4; ++k) {
      #pragma unroll
      for (int m = 0; m < 10; ++m) {
#if HAS_FDOT2
        if (m & 1) accB[k] = __builtin_amdgcn_fdot2(w2[2 * k + m], kr2[m], accB[k], false);
        else       accA[k] = __builtin_amdgcn_fdot2(w2[2 * k + m], kr2[m], accA[k], false);
#else
        const float t = (float)w2[2 * k + m].x * (float)kr2[m].x
                      + (float)w2[2 * k + m].y * (float)kr2[m].y;
        if (m & 1) accB[k] += t; else accA[k] += t;
#endif
      }
    }
  }

  const int oi = TH * by + ty;
  float* orow = outg + ((size_t)bz * OHW + oi) * OHW + TW * bxt + 4 * tx;
  #pragma unroll
  for (int k = 0; k < 4; ++k) orow[k] = accA[k] + accB[k];
}

// ---------------- edge fixup: masked-separable recompute of rows/cols {0,1,255} ----------------
__global__ __launch_bounds__(128) void dgp_edgefix(
    const float* __restrict__ inp, const float* __restrict__ mtfp,
    const int* __restrict__ rp, const int* __restrict__ cp,
    float* __restrict__ outg) {
  __shared__ __align__(16) float tile[20 * ESPAN];
  __shared__ __align__(16) float ck[400];
  __shared__ float kva[180];
  __shared__ float mlds[81];
  __shared__ float avs[12], bvs[12];

  const int tid = threadIdx.x;
  const int bx = blockIdx.x, by = blockIdx.y, bz = blockIdx.z;
  const bool isRow = (by < 3);
  const int segi = isRow ? by : by - 3;
  const int fixedo = (segi == 2) ? 255 : segi;
  const int chC = bz & 7;
  const int rv = rp[bz], cv = cp[bz];
  const int ri = rv >> 1, rf = rv & 1, ci = cv >> 1, cf = cv & 1;

  if (tid < 12) {
    float av = rf ? DEC12c[tid] : (tid == 6 ? 1.f : 0.f);
    if (isRow) {
      const int xi = (2 + 4 * fixedo - ri) - 6 + tid;
      if (xi < 0 || xi >= HH) av = 0.f;
    }
    avs[tid] = av;
  } else if (tid < 24) {
    const int q = tid - 12;
    float bv = cf ? DEC12c[q] : (q == 6 ? 1.f : 0.f);
    if (!isRow) {
      const int xj = (2 + 4 * fixedo - ci) - 6 + q;
      if (xj < 0 || xj >= HH) bv = 0.f;
    }
    bvs[q] = bv;
  } else if (tid < 105) {
    const int m = tid - 24; mlds[m] = mtfp[m * 8 + chC];
  }
  __syncthreads();

  for (int i = tid; i < 180; i += 128) {
    const int S = i / 9, v = i - S * 9;
    const int plo = (S - 8 > 0) ? S - 8 : 0, phi = (S < 11) ? S : 11;
    float s1 = 0.f;
    for (int p = plo; p <= phi; ++p) s1 += avs[p] * mlds[(S - p) * 9 + v];
    kva[i] = s1;
  }
  __syncthreads();
  for (int i = tid; i < 400; i += 128) {
    const int S = i / 20, T = i - S * 20;
    const int qlo = (T - 8 > 0) ? T - 8 : 0, qhi = (T < 11) ? T : 11;
    float s1 = 0.f;
    for (int q = qlo; q <= qhi; ++q) s1 += bvs[q] * kva[S * 9 + (T - q)];
    ck[i] = s1;
  }

  const float* src = inp + ((size_t)bz << 20);
  if (isRow) {
    const int R0 = (2 + 4 * fixedo - ri) - 10;
    const int C0c = 512 * bx - 8 - ci;
    for (int i = tid; i < 20 * ECHUNK; i += 128) {
      const int rr = i / ECHUNK, jc = i - rr * ECHUNK;
      const float* grow = src + (clampi(R0 + rr) << 10);
      const int c0 = C0c + 4 * jc;
      float4 v;
      v.x = grow[clampi(c0 + 0)];
      v.y = grow[clampi(c0 + 1)];
      v.z = grow[clampi(c0 + 2)];
      v.w = grow[clampi(c0 + 3)];
      *(float4*)(tile + rr * ESPAN + 4 * jc) = v;
    }
  } else {
    const int Cw0 = (2 + 4 * fixedo - ci) - 10;
    const int Rr0 = 512 * bx - 8 - ri;
    for (int i = tid; i < 20 * ESPAN; i += 128) {
      const int T = i / ESPAN, rr = i - T * ESPAN;
      tile[T * ESPAN + rr] = src[(clampi(Rr0 + rr) << 10) + clampi(Cw0 + T)];
    }
  }
  __syncthreads();

  float acc = 0.f;
  #pragma unroll 4
  for (int L = 0; L < 20; ++L) {
    const float* wp = tile + L * ESPAN + 4 * tid;
    float w[20];
    #pragma unroll
    for (int j = 0; j < 5; ++j) {
      const float4 v = *(const float4*)(wp + 4 * j);
      w[4 * j] = v.x; w[4 * j + 1] = v.y; w[4 * j + 2] = v.z; w[4 * j + 3] = v.w;
    }
    if (isRow) {
      #pragma unroll
      for (int e = 0; e < 20; ++e) acc += ck[L * 20 + e] * w[e];
    } else {
      #pragma unroll
      for (int e = 0; e < 20; ++e) acc += ck[e * 20 + L] * w[e];
    }
  }

  int oi, oj;
  if (isRow) { oi = fixedo; oj = 128 * bx + tid; }
  else       { oj = fixedo; oi = 128 * bx + tid; }
  outg[((size_t)bz * OHW + oi) * OHW + oj] = acc;
}

// ---------------- corner fixup ----------------
__global__ __launch_bounds__(64) void dgp_cornerfix(
    const float* __restrict__ inp, const float* __restrict__ mtfp,
    const int* __restrict__ rp, const int* __restrict__ cp,
    float* __restrict__ outg) {
  __shared__ float mlds[81];
  __shared__ float avs[12], bvs[12];
  const int lane = threadIdx.x;
  const int bi = blockIdx.x, bj = blockIdx.y, bz = blockIdx.z;
  const int oi = (bi == 2) ? 255 : bi;
  const int oj = (bj == 2) ? 255 : bj;
  const int chC = bz & 7;
  const int rv = rp[bz], cv = cp[bz];
  const int ri = rv >> 1, rf = rv & 1, ci = cv >> 1, cf = cv & 1;

  if (lane < 12)       avs[lane] = rf ? DEC12c[lane] : (lane == 6 ? 1.f : 0.f);
  else if (lane < 24)  bvs[lane - 12] = cf ? DEC12c[lane - 12] : (lane - 12 == 6 ? 1.f : 0.f);
  for (int m = lane; m < 81; m += 64) mlds[m] = mtfp[m * 8 + chC];
  __syncthreads();

  const int Ri = 2 + 4 * oi - ri;
  const int Cj = 2 + 4 * oj - ci;
  const float* src = inp + ((size_t)bz << 20);

  float acc = 0.f;
  for (int pair = lane; pair < 144; pair += 64) {
    const int p = pair / 12, q = pair - 12 * (pair / 12);
    const int xi = Ri - 6 + p, xj = Cj - 6 + q;
    if (xi < 0 || xi >= HH || xj < 0 || xj >= HH) continue;
    const float ab = avs[p] * bvs[q];
    if (ab == 0.f) continue;
    float s = 0.f;
    #pragma unroll
    for (int u = 0; u < 9; ++u) {
      const float* grow = src + (clampi(xi - 4 + u) << 10);
      #pragma unroll
      for (int v = 0; v < 9; ++v) s += mlds[u * 9 + v] * grow[clampi(xj - 4 + v)];
    }
    acc += ab * s;
  }
  #pragma unroll
  for (int off = 32; off > 0; off >>= 1) acc += __shfl_down(acc, off);
  if (lane == 0) outg[((size_t)bz * OHW + oi) * OHW + oj] = acc;
}

extern "C" void kernel_launch(void* const* d_in, const int* in_sizes, int n_in,
                              void* d_out, int out_size, void* d_ws, size_t ws_size,
                              hipStream_t stream) {
  const float* inp  = (const float*)d_in[0];
  const float* mtfp = (const float*)d_in[1];
  const int*   rp   = (const int*)d_in[2];
  const int*   cp   = (const int*)d_in[3];
  float* outg = (float*)d_out;
  hipLaunchKernelGGL(dgp_main, dim3(OHW / TW, OHW / TH, 32), dim3(NTHREADS), 0, stream,
                     inp, mtfp, rp, cp, outg);
  hipLaunchKernelGGL(dgp_edgefix, dim3(2, 6, 32), dim3(128), 0, stream,
                     inp, mtfp, rp, cp, outg);
  hipLaunchKernelGGL(dgp_cornerfix, dim3(3, 3, 32), dim3(64), 0, stream,
                     inp, mtfp, rp, cp, outg);
}

// Round 8
// 154.698 us; speedup vs baseline: 11.2964x; 1.0065x over previous
//
#include <hip/hip_runtime.h>

typedef _Float16 half2v __attribute__((ext_vector_type(2)));

#define HH 1024
#define OHW 256
#define TH 16
#define TW 64
#define NR 80        // input-tile rows
#define NCH 34       // data chunks (8 halves) per row = 272 cols
#define TCHP 36      // padded chunks per row
#define ROWH (TCHP*8) // 288 halves per row
#define NTHREADS 256
#define ESPAN 528
#define ECHUNK (ESPAN/4)

#if defined(__has_builtin)
#  if __has_builtin(__builtin_amdgcn_fdot2)
#    define HAS_FDOT2 1
#  endif
#endif
#ifndef HAS_FDOT2
#  define HAS_FDOT2 0
#endif

__constant__ float DEC12c[12] = {
  -1.20162964e-04f,  1.615524292e-03f, -1.0385513306e-02f,  4.3619155884e-02f,
  -1.45397186478e-01f, 6.10668182370e-01f, 6.10668182370e-01f, -1.45397186478e-01f,
   4.3619155884e-02f, -1.0385513306e-02f,  1.615524292e-03f, -1.20162964e-04f
};

__device__ __forceinline__ int clampi(int v) { return v < 0 ? 0 : (v > HH - 1 ? HH - 1 : v); }

// chunk swizzle: spread same-row lanes over all 8 bank-spans, vary per 4-row group
__device__ __forceinline__ int swzc(int c, int r) {
  return c ^ ((c >> 3) & 1) ^ ((r >> 2) & 3);
}

__device__ __forceinline__ float dot2acc(half2v w, half2v k, float acc) {
#if HAS_FDOT2
  return __builtin_amdgcn_fdot2(w, k, acc, false);
#else
  return acc + (float)w.x * (float)k.x + (float)w.y * (float)k.y;
#endif
}

// ---------------- main kernel: f16 tile + dot2, double-buffered s-pipeline ----------------
__global__ __launch_bounds__(NTHREADS, 3) void dgp_main(
    const float* __restrict__ inp, const float* __restrict__ mtfp,
    const int* __restrict__ rp, const int* __restrict__ cp,
    float* __restrict__ outg) {
  __shared__ __align__(64) _Float16 tile[NR * ROWH];   // 46080 B
  __shared__ __align__(64) half2v ckh[20 * 16];        // row stride 16 half2 (10 used)
  __shared__ float kva[180];
  __shared__ float mlds[81];
  __shared__ float avs[12], bvs[12];

  const int tid = threadIdx.x;
  const int bxt = blockIdx.x, by = blockIdx.y, bz = blockIdx.z;
  const int chC = bz & 7;
  const int rv = rp[bz], cv = cp[bz];
  const int ri = rv >> 1, rf = rv & 1, ci = cv >> 1, cf = cv & 1;
  const int Ri0 = 2 + 4 * TH * by - ri;
  const int Cj0 = 2 + 4 * TW * bxt - ci;
  const int R0 = Ri0 - 10, C0 = Cj0 - 10;

  if (tid < 12)       avs[tid] = rf ? DEC12c[tid] : (tid == 6 ? 1.f : 0.f);
  else if (tid < 24)  bvs[tid - 12] = cf ? DEC12c[tid - 12] : (tid - 12 == 6 ? 1.f : 0.f);
  else if (tid < 105) { const int m = tid - 24; mlds[m] = mtfp[m * 8 + chC]; }
  __syncthreads();

  for (int i = tid; i < 180; i += NTHREADS) {
    const int S = i / 9, v = i - S * 9;
    const int plo = (S - 8 > 0) ? S - 8 : 0, phi = (S < 11) ? S : 11;
    float s1 = 0.f;
    for (int p = plo; p <= phi; ++p) s1 += avs[p] * mlds[(S - p) * 9 + v];
    kva[i] = s1;
  }
  __syncthreads();

  // combined 20x20 kernel, packed to half2 pairs
  for (int i = tid; i < 200; i += NTHREADS) {
    const int S = i / 10, m = i - S * 10;
    float s[2];
    #pragma unroll
    for (int h = 0; h < 2; ++h) {
      const int T = 2 * m + h;
      const int qlo = (T - 8 > 0) ? T - 8 : 0, qhi = (T < 11) ? T : 11;
      float acc = 0.f;
      for (int q = qlo; q <= qhi; ++q) acc += bvs[q] * kva[S * 9 + (T - q)];
      s[h] = acc;
    }
    half2v hv; hv.x = (_Float16)s[0]; hv.y = (_Float16)s[1];
    ckh[S * 16 + m] = hv;
  }

  // stage 80x272 tile as f16, swizzled chunks; per-chunk interior fast path
  const float* src = inp + ((size_t)bz << 20);
  for (int idx = tid; idx < NR * NCH; idx += NTHREADS) {
    const int rr = idx / NCH, g = idx - rr * NCH;
    const float* grow = src + (clampi(R0 + rr) << 10);
    const int c0 = C0 + 8 * g;
    float v[8];
    if (c0 >= 0 && c0 + 7 <= HH - 1) {
      __builtin_memcpy(v, grow + c0, 32);
    } else {
      #pragma unroll
      for (int i = 0; i < 8; ++i) v[i] = grow[clampi(c0 + i)];
    }
    _Float16 h[8];
    #pragma unroll
    for (int i = 0; i < 8; ++i) h[i] = (_Float16)v[i];
    __builtin_memcpy(tile + rr * ROWH + (swzc(g, rr) << 3), h, 16);
  }
  __syncthreads();

  const int ty = tid >> 4;   // 0..15
  const int tx = tid & 15;   // 0..15
  const int rbase = 4 * ty;
  float accA[4] = {0.f, 0.f, 0.f, 0.f}, accB[4] = {0.f, 0.f, 0.f, 0.f};

#define LOADKR(dst, s) __builtin_memcpy(dst, &ckh[(s) * 16], 40)
#define LOADW(dst, s) do {                                              \
    const int r_ = rbase + (s);                                         \
    const _Float16* rowp_ = tile + r_ * ROWH;                           \
    const int mr_ = (r_ >> 2) & 3;                                      \
    __builtin_memcpy(&dst[0],  rowp_ + (swzc(2 * tx + 0, r_) << 3), 16);\
    __builtin_memcpy(&dst[4],  rowp_ + (swzc(2 * tx + 1, r_) << 3), 16);\
    __builtin_memcpy(&dst[8],  rowp_ + (swzc(2 * tx + 2, r_) << 3), 16);\
    __builtin_memcpy(&dst[12], rowp_ + (swzc(2 * tx + 3, r_) << 3), 16);\
    (void)mr_;                                                          \
  } while (0)
#define COMPUTE(w2, kr2) do {                                           \
    _Pragma("unroll")                                                   \
    for (int k = 0; k < 4; ++k) {                                       \
      _Pragma("unroll")                                                 \
      for (int m = 0; m < 10; ++m) {                                    \
        if (m & 1) accB[k] = dot2acc(w2[2 * k + m], kr2[m], accB[k]);   \
        else       accA[k] = dot2acc(w2[2 * k + m], kr2[m], accA[k]);   \
      }                                                                 \
    }                                                                   \
  } while (0)

  half2v krA[10], krB[10], wA[16], wB[16];
  LOADKR(krA, 0);
  LOADW(wA, 0);
  #pragma unroll
  for (int sp = 0; sp < 10; ++sp) {
    const int s1 = 2 * sp + 1, s2 = 2 * sp + 2;
    if (s1 < 20) { LOADKR(krB, s1); LOADW(wB, s1); }
    COMPUTE(wA, krA);
    if (s2 < 20) { LOADKR(krA, s2); LOADW(wA, s2); }
    if (s1 < 20) COMPUTE(wB, krB);
  }
#undef LOADKR
#undef LOADW
#undef COMPUTE

  const int oi = TH * by + ty;
  float* orow = outg + ((size_t)bz * OHW + oi) * OHW + TW * bxt + 4 * tx;
  #pragma unroll
  for (int k = 0; k < 4; ++k) orow[k] = accA[k] + accB[k];
}

// ---------------- edge fixup: masked-separable recompute of rows/cols {0,1,255} ----------------
__global__ __launch_bounds__(128) void dgp_edgefix(
    const float* __restrict__ inp, const float* __restrict__ mtfp,
    const int* __restrict__ rp, const int* __restrict__ cp,
    float* __restrict__ outg) {
  __shared__ __align__(16) float tile[20 * ESPAN];
  __shared__ __align__(16) float ck[400];
  __shared__ float kva[180];
  __shared__ float mlds[81];
  __shared__ float avs[12], bvs[12];

  const int tid = threadIdx.x;
  const int bx = blockIdx.x, by = blockIdx.y, bz = blockIdx.z;
  const bool isRow = (by < 3);
  const int segi = isRow ? by : by - 3;
  const int fixedo = (segi == 2) ? 255 : segi;
  const int chC = bz & 7;
  const int rv = rp[bz], cv = cp[bz];
  const int ri = rv >> 1, rf = rv & 1, ci = cv >> 1, cf = cv & 1;

  if (tid < 12) {
    float av = rf ? DEC12c[tid] : (tid == 6 ? 1.f : 0.f);
    if (isRow) {
      const int xi = (2 + 4 * fixedo - ri) - 6 + tid;
      if (xi < 0 || xi >= HH) av = 0.f;
    }
    avs[tid] = av;
  } else if (tid < 24) {
    const int q = tid - 12;
    float bv = cf ? DEC12c[q] : (q == 6 ? 1.f : 0.f);
    if (!isRow) {
      const int xj = (2 + 4 * fixedo - ci) - 6 + q;
      if (xj < 0 || xj >= HH) bv = 0.f;
    }
    bvs[q] = bv;
  } else if (tid < 105) {
    const int m = tid - 24; mlds[m] = mtfp[m * 8 + chC];
  }
  __syncthreads();

  for (int i = tid; i < 180; i += 128) {
    const int S = i / 9, v = i - S * 9;
    const int plo = (S - 8 > 0) ? S - 8 : 0, phi = (S < 11) ? S : 11;
    float s1 = 0.f;
    for (int p = plo; p <= phi; ++p) s1 += avs[p] * mlds[(S - p) * 9 + v];
    kva[i] = s1;
  }
  __syncthreads();
  for (int i = tid; i < 400; i += 128) {
    const int S = i / 20, T = i - S * 20;
    const int qlo = (T - 8 > 0) ? T - 8 : 0, qhi = (T < 11) ? T : 11;
    float s1 = 0.f;
    for (int q = qlo; q <= qhi; ++q) s1 += bvs[q] * kva[S * 9 + (T - q)];
    ck[i] = s1;
  }

  const float* src = inp + ((size_t)bz << 20);
  if (isRow) {
    const int R0 = (2 + 4 * fixedo - ri) - 10;
    const int C0c = 512 * bx - 8 - ci;
    for (int i = tid; i < 20 * ECHUNK; i += 128) {
      const int rr = i / ECHUNK, jc = i - rr * ECHUNK;
      const float* grow = src + (clampi(R0 + rr) << 10);
      const int c0 = C0c + 4 * jc;
      float4 v;
      v.x = grow[clampi(c0 + 0)];
      v.y = grow[clampi(c0 + 1)];
      v.z = grow[clampi(c0 + 2)];
      v.w = grow[clampi(c0 + 3)];
      *(float4*)(tile + rr * ESPAN + 4 * jc) = v;
    }
  } else {
    const int Cw0 = (2 + 4 * fixedo - ci) - 10;
    const int Rr0 = 512 * bx - 8 - ri;
    for (int i = tid; i < 20 * ESPAN; i += 128) {
      const int T = i / ESPAN, rr = i - T * ESPAN;
      tile[T * ESPAN + rr] = src[(clampi(Rr0 + rr) << 10) + clampi(Cw0 + T)];
    }
  }
  __syncthreads();

  float acc = 0.f;
  #pragma unroll 4
  for (int L = 0; L < 20; ++L) {
    const float* wp = tile + L * ESPAN + 4 * tid;
    float w[20];
    #pragma unroll
    for (int j = 0; j < 5; ++j) {
      const float4 v = *(const float4*)(wp + 4 * j);
      w[4 * j] = v.x; w[4 * j + 1] = v.y; w[4 * j + 2] = v.z; w[4 * j + 3] = v.w;
    }
    if (isRow) {
      #pragma unroll
      for (int e = 0; e < 20; ++e) acc += ck[L * 20 + e] * w[e];
    } else {
      #pragma unroll
      for (int e = 0; e < 20; ++e) acc += ck[e * 20 + L] * w[e];
    }
  }

  int oi, oj;
  if (isRow) { oi = fixedo; oj = 128 * bx + tid; }
  else       { oj = fixedo; oi = 128 * bx + tid; }
  outg[((size_t)bz * OHW + oi) * OHW + oj] = acc;
}

// ---------------- corner fixup ----------------
__global__ __launch_bounds__(64) void dgp_cornerfix(
    const float* __restrict__ inp, const float* __restrict__ mtfp,
    const int* __restrict__ rp, const int* __restrict__ cp,
    float* __restrict__ outg) {
  __shared__ float mlds[81];
  __shared__ float avs[12], bvs[12];
  const int lane = threadIdx.x;
  const int bi = blockIdx.x, bj = blockIdx.y, bz = blockIdx.z;
  const int oi = (bi == 2) ? 255 : bi;
  const int oj = (bj == 2) ? 255 : bj;
  const int chC = bz & 7;
  const int rv = rp[bz], cv = cp[bz];
  const int ri = rv >> 1, rf = rv & 1, ci = cv >> 1, cf = cv & 1;

  if (lane < 12)       avs[lane] = rf ? DEC12c[lane] : (lane == 6 ? 1.f : 0.f);
  else if (lane < 24)  bvs[lane - 12] = cf ? DEC12c[lane - 12] : (lane - 12 == 6 ? 1.f : 0.f);
  for (int m = lane; m < 81; m += 64) mlds[m] = mtfp[m * 8 + chC];
  __syncthreads();

  const int Ri = 2 + 4 * oi - ri;
  const int Cj = 2 + 4 * oj - ci;
  const float* src = inp + ((size_t)bz << 20);

  float acc = 0.f;
  for (int pair = lane; pair < 144; pair += 64) {
    const int p = pair / 12, q = pair - 12 * (pair / 12);
    const int xi = Ri - 6 + p, xj = Cj - 6 + q;
    if (xi < 0 || xi >= HH || xj < 0 || xj >= HH) continue;
    const float ab = avs[p] * bvs[q];
    if (ab == 0.f) continue;
    float s = 0.f;
    #pragma unroll
    for (int u = 0; u < 9; ++u) {
      const float* grow = src + (clampi(xi - 4 + u) << 10);
      #pragma unroll
      for (int v = 0; v < 9; ++v) s += mlds[u * 9 + v] * grow[clampi(xj - 4 + v)];
    }
    acc += ab * s;
  }
  #pragma unroll
  for (int off = 32; off > 0; off >>= 1) acc += __shfl_down(acc, off);
  if (lane == 0) outg[((size_t)bz * OHW + oi) * OHW + oj] = acc;
}

extern "C" void kernel_launch(void* const* d_in, const int* in_sizes, int n_in,
                              void* d_out, int out_size, void* d_ws, size_t ws_size,
                              hipStream_t stream) {
  const float* inp  = (const float*)d_in[0];
  const float* mtfp = (const float*)d_in[1];
  const int*   rp   = (const int*)d_in[2];
  const int*   cp   = (const int*)d_in[3];
  float* outg = (float*)d_out;
  hipLaunchKernelGGL(dgp_main, dim3(OHW / TW, OHW / TH, 32), dim3(NTHREADS), 0, stream,
                     inp, mtfp, rp, cp, outg);
  hipLaunchKernelGGL(dgp_edgefix, dim3(2, 6, 32), dim3(128), 0, stream,
                     inp, mtfp, rp, cp, outg);
  hipLaunchKernelGGL(dgp_cornerfix, dim3(3, 3, 32), dim3(64), 0, stream,
                     inp, mtfp, rp, cp, outg);
}

// Round 9
// 154.437 us; speedup vs baseline: 11.3155x; 1.0017x over previous
//
#include <hip/hip_runtime.h>

typedef _Float16 half2v __attribute__((ext_vector_type(2)));
typedef _Float16 half4v __attribute__((ext_vector_type(4)));
typedef _Float16 half8v __attribute__((ext_vector_type(8)));

#define HH 1024
#define OHW 256
#define TH 16
#define TW 64
#define NR 80        // input-tile rows
#define NCH 34       // data chunks (8 halves) per row = 272 cols
#define TCHP 36      // padded chunks per row
#define ROWH (TCHP*8) // 288 halves per row
#define NTHREADS 256
#define ESPAN 528
#define ECHUNK (ESPAN/4)

#if defined(__has_builtin)
#  if __has_builtin(__builtin_amdgcn_fdot2)
#    define HAS_FDOT2 1
#  endif
#endif
#ifndef HAS_FDOT2
#  define HAS_FDOT2 0
#endif

__constant__ float DEC12c[12] = {
  -1.20162964e-04f,  1.615524292e-03f, -1.0385513306e-02f,  4.3619155884e-02f,
  -1.45397186478e-01f, 6.10668182370e-01f, 6.10668182370e-01f, -1.45397186478e-01f,
   4.3619155884e-02f, -1.0385513306e-02f,  1.615524292e-03f, -1.20162964e-04f
};

__device__ __forceinline__ int clampi(int v) { return v < 0 ? 0 : (v > HH - 1 ? HH - 1 : v); }

// chunk swizzle: spread same-row lanes over all 8 bank-spans, vary per 4-row group
__device__ __forceinline__ int swzc(int c, int r) {
  return c ^ ((c >> 3) & 1) ^ ((r >> 2) & 3);
}

__device__ __forceinline__ half2v mk2(_Float16 a, _Float16 b) {
  half2v r; r.x = a; r.y = b; return r;
}

// compile-time half2 select from 16-half2 window held in 4 named half8 regs
template<int J>
__device__ __forceinline__ half2v sel(half8v a, half8v b, half8v c, half8v d) {
  constexpr int V = J >> 2, E = J & 3;
  const half8v s = (V == 0) ? a : (V == 1) ? b : (V == 2) ? c : d;
  return mk2(s[2 * E], s[2 * E + 1]);
}
template<int E>
__device__ __forceinline__ half2v g2(half8v v) { return mk2(v[2 * E], v[2 * E + 1]); }

__device__ __forceinline__ float dot2acc(half2v w, half2v k, float acc) {
#if HAS_FDOT2
  return __builtin_amdgcn_fdot2(w, k, acc, false);
#else
  return acc + (float)w.x * (float)k.x + (float)w.y * (float)k.y;
#endif
}

// ---------------- main kernel: f16 tile + dot2, array-free 2-deep pipeline ----------------
__global__ __launch_bounds__(NTHREADS, 3) void dgp_main(
    const float* __restrict__ inp, const float* __restrict__ mtfp,
    const int* __restrict__ rp, const int* __restrict__ cp,
    float* __restrict__ outg) {
  __shared__ __align__(64) _Float16 tile[NR * ROWH];   // 46080 B
  __shared__ __align__(64) half2v ckh[20 * 16];        // row stride 16 half2 (10 used)
  __shared__ float kva[180];
  __shared__ float mlds[81];
  __shared__ float avs[12], bvs[12];

  const int tid = threadIdx.x;
  const int bxt = blockIdx.x, by = blockIdx.y, bz = blockIdx.z;
  const int chC = bz & 7;
  const int rv = rp[bz], cv = cp[bz];
  const int ri = rv >> 1, rf = rv & 1, ci = cv >> 1, cf = cv & 1;
  const int Ri0 = 2 + 4 * TH * by - ri;
  const int Cj0 = 2 + 4 * TW * bxt - ci;
  const int R0 = Ri0 - 10, C0 = Cj0 - 10;

  if (tid < 12)       avs[tid] = rf ? DEC12c[tid] : (tid == 6 ? 1.f : 0.f);
  else if (tid < 24)  bvs[tid - 12] = cf ? DEC12c[tid - 12] : (tid - 12 == 6 ? 1.f : 0.f);
  else if (tid < 105) { const int m = tid - 24; mlds[m] = mtfp[m * 8 + chC]; }
  __syncthreads();

  for (int i = tid; i < 180; i += NTHREADS) {
    const int S = i / 9, v = i - S * 9;
    const int plo = (S - 8 > 0) ? S - 8 : 0, phi = (S < 11) ? S : 11;
    float s1 = 0.f;
    for (int p = plo; p <= phi; ++p) s1 += avs[p] * mlds[(S - p) * 9 + v];
    kva[i] = s1;
  }
  __syncthreads();

  // combined 20x20 kernel, packed to half2 pairs
  for (int i = tid; i < 200; i += NTHREADS) {
    const int S = i / 10, m = i - S * 10;
    float s[2];
    #pragma unroll
    for (int h = 0; h < 2; ++h) {
      const int T = 2 * m + h;
      const int qlo = (T - 8 > 0) ? T - 8 : 0, qhi = (T < 11) ? T : 11;
      float acc = 0.f;
      for (int q = qlo; q <= qhi; ++q) acc += bvs[q] * kva[S * 9 + (T - q)];
      s[h] = acc;
    }
    half2v hv; hv.x = (_Float16)s[0]; hv.y = (_Float16)s[1];
    ckh[S * 16 + m] = hv;
  }

  // stage 80x272 tile as f16, swizzled chunks; per-chunk interior fast path
  const float* src = inp + ((size_t)bz << 20);
  for (int idx = tid; idx < NR * NCH; idx += NTHREADS) {
    const int rr = idx / NCH, g = idx - rr * NCH;
    const float* grow = src + (clampi(R0 + rr) << 10);
    const int c0 = C0 + 8 * g;
    float v[8];
    if (c0 >= 0 && c0 + 7 <= HH - 1) {
      __builtin_memcpy(v, grow + c0, 32);
    } else {
      #pragma unroll
      for (int i = 0; i < 8; ++i) v[i] = grow[clampi(c0 + i)];
    }
    _Float16 h[8];
    #pragma unroll
    for (int i = 0; i < 8; ++i) h[i] = (_Float16)v[i];
    __builtin_memcpy(tile + rr * ROWH + (swzc(g, rr) << 3), h, 16);
  }
  __syncthreads();

  const int ty = tid >> 4;   // 0..15
  const int tx = tid & 15;   // 0..15
  const int rbase = 4 * ty;

  half8v wa0, wa1, wa2, wa3, wb0, wb1, wb2, wb3;
  half8v ka0, ka1, kb0, kb1;
  half4v ka2, kb2;
  float a0 = 0.f, a1 = 0.f, a2 = 0.f, a3 = 0.f;
  float b0 = 0.f, b1 = 0.f, b2 = 0.f, b3 = 0.f;

#define STG(W0, W1, W2x, W3x, K0, K1, K2x, s) do {                       \
    const int r_ = rbase + (s);                                          \
    const _Float16* rp_ = tile + r_ * ROWH;                              \
    W0 = *(const half8v*)(rp_ + (swzc(2 * tx + 0, r_) << 3));            \
    W1 = *(const half8v*)(rp_ + (swzc(2 * tx + 1, r_) << 3));            \
    W2x = *(const half8v*)(rp_ + (swzc(2 * tx + 2, r_) << 3));           \
    W3x = *(const half8v*)(rp_ + (swzc(2 * tx + 3, r_) << 3));           \
    const _Float16* kp_ = (const _Float16*)(ckh + (s) * 16);             \
    K0 = *(const half8v*)(kp_);                                          \
    K1 = *(const half8v*)(kp_ + 8);                                      \
    K2x = *(const half4v*)(kp_ + 16);                                    \
  } while (0)

#define ROWK(o, W0, W1, W2x, W3x, K0, K1, K2x, A, B)                     \
    A = dot2acc(sel<(o) + 0>(W0, W1, W2x, W3x), g2<0>(K0), A);           \
    B = dot2acc(sel<(o) + 1>(W0, W1, W2x, W3x), g2<1>(K0), B);           \
    A = dot2acc(sel<(o) + 2>(W0, W1, W2x, W3x), g2<2>(K0), A);           \
    B = dot2acc(sel<(o) + 3>(W0, W1, W2x, W3x), g2<3>(K0), B);           \
    A = dot2acc(sel<(o) + 4>(W0, W1, W2x, W3x), g2<0>(K1), A);           \
    B = dot2acc(sel<(o) + 5>(W0, W1, W2x, W3x), g2<1>(K1), B);           \
    A = dot2acc(sel<(o) + 6>(W0, W1, W2x, W3x), g2<2>(K1), A);           \
    B = dot2acc(sel<(o) + 7>(W0, W1, W2x, W3x), g2<3>(K1), B);           \
    A = dot2acc(sel<(o) + 8>(W0, W1, W2x, W3x), mk2(K2x[0], K2x[1]), A); \
    B = dot2acc(sel<(o) + 9>(W0, W1, W2x, W3x), mk2(K2x[2], K2x[3]), B);

#define STG_A(s) STG(wa0, wa1, wa2, wa3, ka0, ka1, ka2, s)
#define STG_B(s) STG(wb0, wb1, wb2, wb3, kb0, kb1, kb2, s)
#define COMP_A                                                           \
    ROWK(0, wa0, wa1, wa2, wa3, ka0, ka1, ka2, a0, b0)                   \
    ROWK(2, wa0, wa1, wa2, wa3, ka0, ka1, ka2, a1, b1)                   \
    ROWK(4, wa0, wa1, wa2, wa3, ka0, ka1, ka2, a2, b2)                   \
    ROWK(6, wa0, wa1, wa2, wa3, ka0, ka1, ka2, a3, b3)
#define COMP_B                                                           \
    ROWK(0, wb0, wb1, wb2, wb3, kb0, kb1, kb2, a0, b0)                   \
    ROWK(2, wb0, wb1, wb2, wb3, kb0, kb1, kb2, a1, b1)                   \
    ROWK(4, wb0, wb1, wb2, wb3, kb0, kb1, kb2, a2, b2)                   \
    ROWK(6, wb0, wb1, wb2, wb3, kb0, kb1, kb2, a3, b3)
#define PAIR(se) STG_B((se) + 1); COMP_A; STG_A((se) + 2); COMP_B;

  STG_A(0);
  PAIR(0)  PAIR(2)  PAIR(4)  PAIR(6)  PAIR(8)
  PAIR(10) PAIR(12) PAIR(14) PAIR(16)
  STG_B(19); COMP_A; COMP_B;

#undef STG
#undef ROWK
#undef STG_A
#undef STG_B
#undef COMP_A
#undef COMP_B
#undef PAIR

  const int oi = TH * by + ty;
  float* orow = outg + ((size_t)bz * OHW + oi) * OHW + TW * bxt + 4 * tx;
  orow[0] = a0 + b0;
  orow[1] = a1 + b1;
  orow[2] = a2 + b2;
  orow[3] = a3 + b3;
}

// ---------------- edge fixup: masked-separable recompute of rows/cols {0,1,255} ----------------
__global__ __launch_bounds__(128) void dgp_edgefix(
    const float* __restrict__ inp, const float* __restrict__ mtfp,
    const int* __restrict__ rp, const int* __restrict__ cp,
    float* __restrict__ outg) {
  __shared__ __align__(16) float tile[20 * ESPAN];
  __shared__ __align__(16) float ck[400];
  __shared__ float kva[180];
  __shared__ float mlds[81];
  __shared__ float avs[12], bvs[12];

  const int tid = threadIdx.x;
  const int bx = blockIdx.x, by = blockIdx.y, bz = blockIdx.z;
  const bool isRow = (by < 3);
  const int segi = isRow ? by : by - 3;
  const int fixedo = (segi == 2) ? 255 : segi;
  const int chC = bz & 7;
  const int rv = rp[bz], cv = cp[bz];
  const int ri = rv >> 1, rf = rv & 1, ci = cv >> 1, cf = cv & 1;

  if (tid < 12) {
    float av = rf ? DEC12c[tid] : (tid == 6 ? 1.f : 0.f);
    if (isRow) {
      const int xi = (2 + 4 * fixedo - ri) - 6 + tid;
      if (xi < 0 || xi >= HH) av = 0.f;
    }
    avs[tid] = av;
  } else if (tid < 24) {
    const int q = tid - 12;
    float bv = cf ? DEC12c[q] : (q == 6 ? 1.f : 0.f);
    if (!isRow) {
      const int xj = (2 + 4 * fixedo - ci) - 6 + q;
      if (xj < 0 || xj >= HH) bv = 0.f;
    }
    bvs[q] = bv;
  } else if (tid < 105) {
    const int m = tid - 24; mlds[m] = mtfp[m * 8 + chC];
  }
  __syncthreads();

  for (int i = tid; i < 180; i += 128) {
    const int S = i / 9, v = i - S * 9;
    const int plo = (S - 8 > 0) ? S - 8 : 0, phi = (S < 11) ? S : 11;
    float s1 = 0.f;
    for (int p = plo; p <= phi; ++p) s1 += avs[p] * mlds[(S - p) * 9 + v];
    kva[i] = s1;
  }
  __syncthreads();
  for (int i = tid; i < 400; i += 128) {
    const int S = i / 20, T = i - S * 20;
    const int qlo = (T - 8 > 0) ? T - 8 : 0, qhi = (T < 11) ? T : 11;
    float s1 = 0.f;
    for (int q = qlo; q <= qhi; ++q) s1 += bvs[q] * kva[S * 9 + (T - q)];
    ck[i] = s1;
  }

  const float* src = inp + ((size_t)bz << 20);
  if (isRow) {
    const int R0 = (2 + 4 * fixedo - ri) - 10;
    const int C0c = 512 * bx - 8 - ci;
    for (int i = tid; i < 20 * ECHUNK; i += 128) {
      const int rr = i / ECHUNK, jc = i - rr * ECHUNK;
      const float* grow = src + (clampi(R0 + rr) << 10);
      const int c0 = C0c + 4 * jc;
      float4 v;
      v.x = grow[clampi(c0 + 0)];
      v.y = grow[clampi(c0 + 1)];
      v.z = grow[clampi(c0 + 2)];
      v.w = grow[clampi(c0 + 3)];
      *(float4*)(tile + rr * ESPAN + 4 * jc) = v;
    }
  } else {
    const int Cw0 = (2 + 4 * fixedo - ci) - 10;
    const int Rr0 = 512 * bx - 8 - ri;
    for (int i = tid; i < 20 * ESPAN; i += 128) {
      const int T = i / ESPAN, rr = i - T * ESPAN;
      tile[T * ESPAN + rr] = src[(clampi(Rr0 + rr) << 10) + clampi(Cw0 + T)];
    }
  }
  __syncthreads();

  float acc = 0.f;
  #pragma unroll 4
  for (int L = 0; L < 20; ++L) {
    const float* wp = tile + L * ESPAN + 4 * tid;
    float w[20];
    #pragma unroll
    for (int j = 0; j < 5; ++j) {
      const float4 v = *(const float4*)(wp + 4 * j);
      w[4 * j] = v.x; w[4 * j + 1] = v.y; w[4 * j + 2] = v.z; w[4 * j + 3] = v.w;
    }
    if (isRow) {
      #pragma unroll
      for (int e = 0; e < 20; ++e) acc += ck[L * 20 + e] * w[e];
    } else {
      #pragma unroll
      for (int e = 0; e < 20; ++e) acc += ck[e * 20 + L] * w[e];
    }
  }

  int oi, oj;
  if (isRow) { oi = fixedo; oj = 128 * bx + tid; }
  else       { oj = fixedo; oi = 128 * bx + tid; }
  outg[((size_t)bz * OHW + oi) * OHW + oj] = acc;
}

// ---------------- corner fixup ----------------
__global__ __launch_bounds__(64) void dgp_cornerfix(
    const float* __restrict__ inp, const float* __restrict__ mtfp,
    const int* __restrict__ rp, const int* __restrict__ cp,
    float* __restrict__ outg) {
  __shared__ float mlds[81];
  __shared__ float avs[12], bvs[12];
  const int lane = threadIdx.x;
  const int bi = blockIdx.x, bj = blockIdx.y, bz = blockIdx.z;
  const int oi = (bi == 2) ? 255 : bi;
  const int oj = (bj == 2) ? 255 : bj;
  const int chC = bz & 7;
  const int rv = rp[bz], cv = cp[bz];
  const int ri = rv >> 1, rf = rv & 1, ci = cv >> 1, cf = cv & 1;

  if (lane < 12)       avs[lane] = rf ? DEC12c[lane] : (lane == 6 ? 1.f : 0.f);
  else if (lane < 24)  bvs[lane - 12] = cf ? DEC12c[lane - 12] : (lane - 12 == 6 ? 1.f : 0.f);
  for (int m = lane; m < 81; m += 64) mlds[m] = mtfp[m * 8 + chC];
  __syncthreads();

  const int Ri = 2 + 4 * oi - ri;
  const int Cj = 2 + 4 * oj - ci;
  const float* src = inp + ((size_t)bz << 20);

  float acc = 0.f;
  for (int pair = lane; pair < 144; pair += 64) {
    const int p = pair / 12, q = pair - 12 * (pair / 12);
    const int xi = Ri - 6 + p, xj = Cj - 6 + q;
    if (xi < 0 || xi >= HH || xj < 0 || xj >= HH) continue;
    const float ab = avs[p] * bvs[q];
    if (ab == 0.f) continue;
    float s = 0.f;
    #pragma unroll
    for (int u = 0; u < 9; ++u) {
      const float* grow = src + (clampi(xi - 4 + u) << 10);
      #pragma unroll
      for (int v = 0; v < 9; ++v) s += mlds[u * 9 + v] * grow[clampi(xj - 4 + v)];
    }
    acc += ab * s;
  }
  #pragma unroll
  for (int off = 32; off > 0; off >>= 1) acc += __shfl_down(acc, off);
  if (lane == 0) outg[((size_t)bz * OHW + oi) * OHW + oj] = acc;
}

extern "C" void kernel_launch(void* const* d_in, const int* in_sizes, int n_in,
                              void* d_out, int out_size, void* d_ws, size_t ws_size,
                              hipStream_t stream) {
  const float* inp  = (const float*)d_in[0];
  const float* mtfp = (const float*)d_in[1];
  const int*   rp   = (const int*)d_in[2];
  const int*   cp   = (const int*)d_in[3];
  float* outg = (float*)d_out;
  hipLaunchKernelGGL(dgp_main, dim3(OHW / TW, OHW / TH, 32), dim3(NTHREADS), 0, stream,
                     inp, mtfp, rp, cp, outg);
  hipLaunchKernelGGL(dgp_edgefix, dim3(2, 6, 32), dim3(128), 0, stream,
                     inp, mtfp, rp, cp, outg);
  hipLaunchKernelGGL(dgp_cornerfix, dim3(3, 3, 32), dim3(64), 0, stream,
                     inp, mtfp, rp, cp, outg);
}